// Round 3
// baseline (2302.440 us; speedup 1.0000x reference)
//
#include <hip/hip_runtime.h>

// ---------------------------------------------------------------------------
// GenomeDecoder: transformer encoder (tiny) -> 1028 sequential GRU steps ->
// output chunks.
// R5: (1) entire front-end fused into ONE kernel (32 blocks x 512):
//     blocks 0-15 = per-batch transformer (embed..gi0, stage I/O via ws/L2 +
//     __syncthreads, same dataflow as the old 13 kernels), blocks 16-31 =
//     prepm rows (independent, runs concurrently).  3 launches total
//     (front, chain, epi) -> kills ~300us of launch gaps.
// (2) chain: per-lane gate-parity split (par=grp&1) -> 3 transcendentals
//     per step instead of 6; statically-indexed selects (no scratch).
// Chain math unchanged: int8 M (per-row scale) x int8 h via
// mfma_i32_16x16x64_i8, h broadcast rows, exact int32 accumulate.
// ---------------------------------------------------------------------------

typedef unsigned int uint_t;
typedef int v4i __attribute__((ext_vector_type(4)));

// ---- workspace layout (4-byte slot indices) ----
static constexpr size_t WS_HB   = 0;        // 16*16*256
static constexpr size_t WS_QKV  = 65536;    // 16*16*768
static constexpr size_t WS_AO   = 262144;   // 16*16*256
static constexpr size_t WS_F1   = 327680;   // 16*16*1024
static constexpr size_t WS_GI0  = 593920;   // 16*768
static constexpr size_t WS_CV   = 606208;   // 1024 fused-bias consts
static constexpr size_t WS_MS   = 607232;   // 1024 per-row scales
static constexpr size_t WS_M8   = 608256;   // 1024*64 dwords packed int8 M
static constexpr size_t WS_HSEQ = 673792;   // 1028*16*256 floats

__device__ inline float sigf(float x){
    return __builtin_amdgcn_rcpf(1.0f + __builtin_amdgcn_exp2f(-1.442695041f*x));
}
__device__ inline float tanh_fast(float x){
    return 1.0f - 2.0f*__builtin_amdgcn_rcpf(1.0f + __builtin_amdgcn_exp2f(2.885390082f*x));
}

// ======================= fused front-end ===================================
// blocks 0..15: transformer for batch b      (512 threads)
// blocks 16..31: prepm rows [pb*64, pb*64+64) (512 threads)

__global__ __launch_bounds__(512) void k_front(
    const float* gs, const float* eW, const float* eb,
    const float* qkvW, const float* qkvb,
    const float* aoW, const float* aob,
    const float* g1, const float* b1, const float* g2, const float* b2v,
    const float* W1, const float* fb1, const float* W2, const float* fb2,
    const float* Wih, const float* bih,
    const float* Whh, const float* bhh,
    const float* outW, const float* outb,
    float* ws)
{
    __shared__ float s_a[16][256];     // 16 KB general staging
    __shared__ float s_sc[16][16];     // attn scores (one head at a time)
    __shared__ float s_p[2][4];        // LN wave partials (2 halves x 4 waves)
    __shared__ float s_lat[256];
    int tid = threadIdx.x;

    if(blockIdx.x >= 16){
        // ---------------- prepm ----------------
        int pb = blockIdx.x - 16;
        float* wrow = &s_a[0][0];                 // [2][256]
        float* redf = &s_a[2][0];                 // 32 slots used
        signed char* q8 = (signed char*)&s_a[4][0];  // [2][256] bytes
        int rh = tid >> 8, c = tid & 255;
        int wv = tid >> 6;                        // wave 0..7 (0-3 rh0, 4-7 rh1)
        for(int it=0; it<32; ++it){
            int r = pb*64 + it*2 + rh;
            bool hasA = (r < 768);
            wrow[rh*256+c] = hasA ? Wih[(size_t)r*256+c] : 0.0f;
            __syncthreads();                                   // s1
            float m;
            if(hasA){
                float a = 0.f;
                for(int k=0;k<256;++k) a += wrow[rh*256+k]*outW[(size_t)k*256+c];
                if(r<512) a += Whh[(size_t)r*256+c];
                m = a;
            } else {
                m = Whh[(size_t)(r-256)*256+c];
            }
            // fused bias const: sum_c wrow*outb
            float pv = wrow[rh*256+c]*outb[c];
            for(int mk=1; mk<64; mk<<=1) pv += __shfl_xor(pv, mk);
            if((tid&63)==0) redf[wv] = pv;
            __syncthreads();                                   // s2
            if(c==0){
                float cv_sum = redf[rh*4+0]+redf[rh*4+1]+redf[rh*4+2]+redf[rh*4+3];
                float cv;
                if(r<512)       cv = cv_sum + bih[r] + bhh[r];
                else if(r<768)  cv = cv_sum + bih[r];
                else            cv = bhh[r-256];
                ws[WS_CV + r] = cv;
            }
            // per-row absmax (disjoint redf slots 16..23 - no sync needed vs sum reads)
            float av = fabsf(m);
            for(int mk=1; mk<64; mk<<=1) av = fmaxf(av, __shfl_xor(av, mk));
            if((tid&63)==0) redf[16+wv] = av;
            __syncthreads();                                   // s3
            float rowmax = fmaxf(fmaxf(redf[16+rh*4],redf[17+rh*4]),
                                 fmaxf(redf[18+rh*4],redf[19+rh*4]));
            float inv = rowmax>0.f ? 127.0f/rowmax : 0.0f;
            q8[rh*256+c] = (signed char)__float2int_rn(m*inv);
            if(c==0) ws[WS_MS + r] = rowmax>0.f ? rowmax*(1.0f/(127.0f*127.0f)) : 0.0f;
            __syncthreads();                                   // s4
            if(c<64){
                uint_t u = ((uint_t)(unsigned char)q8[rh*256+4*c  ])
                         | ((uint_t)(unsigned char)q8[rh*256+4*c+1] << 8)
                         | ((uint_t)(unsigned char)q8[rh*256+4*c+2] << 16)
                         | ((uint_t)(unsigned char)q8[rh*256+4*c+3] << 24);
                ((uint_t*)ws)[WS_M8 + (size_t)r*64 + c] = u;
            }
            __syncthreads();                                   // s5
        }
        return;
    }

    // ---------------- transformer, batch b ----------------
    int b = blockIdx.x;
    int rh = tid >> 8, ci = tid & 255;
    int wv4 = (tid >> 6) & 3;    // wave index within half

    // embed -> HB
    for(int u=tid; u<4096; u+=512){
        int s=u>>8, i=u&255;
        const float* g = gs + (b*16+s)*16;
        float acc = eb[i];
#pragma unroll
        for(int d=0;d<16;++d) acc += g[d]*eW[i*16+d];
        ws[WS_HB + (size_t)(b*16+s)*256 + i] = acc;
    }
    __syncthreads();

    for(int l=0;l<2;++l){
        // ---- qkv: stage h, compute 768 outputs (reuse w-row over 16 s) ----
        for(int u=tid; u<4096; u+=512)
            s_a[u>>8][u&255] = ws[WS_HB + (size_t)(b*16+(u>>8))*256 + (u&255)];
        __syncthreads();
        for(int j=tid; j<768; j+=512){
            const float* wr = qkvW + (size_t)(l*768+j)*256;
            float bias = qkvb[l*768+j];
            float acc[16];
#pragma unroll
            for(int s=0;s<16;++s) acc[s]=bias;
            for(int k=0;k<256;k+=4){
                float4 w4 = *(const float4*)(wr+k);
#pragma unroll
                for(int s=0;s<16;++s){
                    float4 h4 = *(const float4*)&s_a[s][k];
                    acc[s] += w4.x*h4.x + w4.y*h4.y + w4.z*h4.z + w4.w*h4.w;
                }
            }
            for(int s=0;s<16;++s) ws[WS_QKV + (size_t)(b*16+s)*768 + j] = acc[s];
        }
        __syncthreads();

        // ---- attention, per head ----
        for(int hh=0; hh<4; ++hh){
            for(int u=tid; u<1024; u+=512){
                int s=u>>6, d=u&63;
                const float* base = &ws[WS_QKV + (size_t)(b*16+s)*768 + hh*64 + d];
                s_a[s][d]     = base[0];      // q
                s_a[s][64+d]  = base[256];    // k
                s_a[s][128+d] = base[512];    // v
            }
            __syncthreads();
            if(tid<256){
                int s=tid>>4, t=tid&15;
                float a=0.f;
#pragma unroll
                for(int d=0;d<64;++d) a += s_a[s][d]*s_a[t][64+d];
                s_sc[s][t] = a*0.125f;
            }
            __syncthreads();
            if(tid<16){
                int r=tid;
                float m=-1e30f;
#pragma unroll
                for(int tt=0;tt<16;++tt) m=fmaxf(m,s_sc[r][tt]);
                float e[16]; float sum=0.f;
#pragma unroll
                for(int tt=0;tt<16;++tt){ e[tt]=__expf(s_sc[r][tt]-m); sum+=e[tt]; }
                float inv=1.0f/sum;
#pragma unroll
                for(int tt=0;tt<16;++tt) s_sc[r][tt]=e[tt]*inv;
            }
            __syncthreads();
            for(int u=tid; u<1024; u+=512){
                int s=u>>6, d=u&63;
                float o=0.f;
#pragma unroll
                for(int t2=0;t2<16;++t2) o += s_sc[s][t2]*s_a[t2][128+d];
                ws[WS_AO + (size_t)(b*16+s)*256 + hh*64 + d] = o;
            }
            __syncthreads();
        }

        // ---- attn-out matmul + residual + LN1 -> HB ----
        for(int u=tid; u<4096; u+=512)
            s_a[u>>8][u&255] = ws[WS_AO + (size_t)(b*16+(u>>8))*256 + (u&255)];
        __syncthreads();
        for(int it=0; it<8; ++it){
            int s = it*2 + rh;
            const float* wr = aoW + (size_t)(l*256+ci)*256;
            float acc = aob[l*256+ci];
            for(int k=0;k<256;k+=4){
                float4 w4 = *(const float4*)(wr+k);
                float4 h4 = *(const float4*)&s_a[s][k];
                acc += w4.x*h4.x + w4.y*h4.y + w4.z*h4.z + w4.w*h4.w;
            }
            float x = ws[WS_HB + (size_t)(b*16+s)*256 + ci] + acc;
            float pv = x;
            for(int mk=1;mk<64;mk<<=1) pv += __shfl_xor(pv, mk);
            if((tid&63)==0) s_p[rh][wv4] = pv;
            __syncthreads();
            float mean = (s_p[rh][0]+s_p[rh][1]+s_p[rh][2]+s_p[rh][3])*(1.0f/256.0f);
            float d = x - mean;
            float qv = d*d;
            for(int mk=1;mk<64;mk<<=1) qv += __shfl_xor(qv, mk);
            __syncthreads();
            if((tid&63)==0) s_p[rh][wv4] = qv;
            __syncthreads();
            float var = (s_p[rh][0]+s_p[rh][1]+s_p[rh][2]+s_p[rh][3])*(1.0f/256.0f);
            float y = d / sqrtf(var+1e-5f);
            ws[WS_HB + (size_t)(b*16+s)*256 + ci] = y*g1[l*256+ci] + b1[l*256+ci];
            __syncthreads();
        }

        // ---- ffn1: stage h, 1024 outputs (w-row reuse over 16 s) ----
        for(int u=tid; u<4096; u+=512)
            s_a[u>>8][u&255] = ws[WS_HB + (size_t)(b*16+(u>>8))*256 + (u&255)];
        __syncthreads();
        for(int j=tid; j<1024; j+=512){
            const float* wr = W1 + (size_t)(l*1024+j)*256;
            float bias = fb1[l*1024+j];
            float acc[16];
#pragma unroll
            for(int s=0;s<16;++s) acc[s]=bias;
            for(int k=0;k<256;k+=4){
                float4 w4 = *(const float4*)(wr+k);
#pragma unroll
                for(int s=0;s<16;++s){
                    float4 h4 = *(const float4*)&s_a[s][k];
                    acc[s] += w4.x*h4.x + w4.y*h4.y + w4.z*h4.z + w4.w*h4.w;
                }
            }
            for(int s=0;s<16;++s)
                ws[WS_F1 + (size_t)(b*16+s)*1024 + j] = fmaxf(acc[s],0.0f);
        }
        __syncthreads();

        // ---- ffn2 + residual + LN2 -> HB (2 rows of F1 staged per iter) ----
        {
            float* f1p = &s_a[0][0];   // [2][1024]
            for(int it=0; it<8; ++it){
                for(int u=tid; u<2048; u+=512)
                    f1p[u] = ws[WS_F1 + (size_t)(b*16 + it*2 + (u>>10))*1024 + (u&1023)];
                __syncthreads();
                int s = it*2 + rh;
                const float* wr = W2 + (size_t)(l*256+ci)*1024;
                float acc = fb2[l*256+ci];
                for(int k=0;k<1024;k+=4){
                    float4 w4 = *(const float4*)(wr+k);
                    float4 h4 = *(const float4*)(f1p + rh*1024 + k);
                    acc += w4.x*h4.x + w4.y*h4.y + w4.z*h4.z + w4.w*h4.w;
                }
                float x = ws[WS_HB + (size_t)(b*16+s)*256 + ci] + acc;
                float pv = x;
                for(int mk=1;mk<64;mk<<=1) pv += __shfl_xor(pv, mk);
                if((tid&63)==0) s_p[rh][wv4] = pv;
                __syncthreads();
                float mean = (s_p[rh][0]+s_p[rh][1]+s_p[rh][2]+s_p[rh][3])*(1.0f/256.0f);
                float d = x - mean;
                float qv = d*d;
                for(int mk=1;mk<64;mk<<=1) qv += __shfl_xor(qv, mk);
                __syncthreads();
                if((tid&63)==0) s_p[rh][wv4] = qv;
                __syncthreads();
                float var = (s_p[rh][0]+s_p[rh][1]+s_p[rh][2]+s_p[rh][3])*(1.0f/256.0f);
                float y = d / sqrtf(var+1e-5f);
                ws[WS_HB + (size_t)(b*16+s)*256 + ci] = y*g2[l*256+ci] + b2v[l*256+ci];
                __syncthreads();
            }
        }
    }

    // ---- latent mean + gi0 ----
    if(tid<256){
        float a=0.f;
#pragma unroll
        for(int s=0;s<16;++s) a += ws[WS_HB + (size_t)(b*16+s)*256 + tid];
        s_lat[tid] = a*(1.0f/16.0f);
    }
    __syncthreads();
    for(int j=tid; j<768; j+=512){
        const float* wr = Wih + (size_t)j*256;
        float acc = bih[j];
        for(int k=0;k<256;k+=4){
            float4 w4 = *(const float4*)(wr+k);
            float4 l4 = *(const float4*)&s_lat[k];
            acc += w4.x*l4.x + w4.y*l4.y + w4.z*l4.z + w4.w*l4.w;
        }
        ws[WS_GI0 + (size_t)b*768 + j] = acc;
    }
}

// ======================= sequential GRU chain ==============================
// 16 blocks (one per batch), 512 threads = 8 waves.  Wave w owns h slice
// [w*32, w*32+32): 8 B-fragments (4 gate slices x 2 halves) x 4 K-tiles of
// mfma_i32_16x16x64_i8; A = h broadcast to all 16 rows.  Gate parity split:
// lane (col,grp) tracks only element ge = w*32 + (grp&1)*16 + col -> 3
// transcendentals/step.  h double-buffered in LDS; raw s_barrier +
// lgkmcnt-only wait (global h stores never drain vmcnt in-loop).

__global__ __launch_bounds__(512,2) void k_chain(const float* bhh, float* ws){
    __shared__ alignas(16) signed char h8[2][256];
    int tid = threadIdx.x;
    int b   = blockIdx.x;
    int l   = tid & 63;
    int w   = tid >> 6;
    int col = l & 15;
    int grp = l >> 4;
    int par = grp & 1;
    int ge  = w*32 + par*16 + col;    // this lane's h element

    const uint_t* Mdw = (const uint_t*)ws + WS_M8;

    // B fragments (all 8 needed for the MFMAs)
    v4i wf[8][4];
#pragma unroll
    for(int s=0;s<4;++s){
#pragma unroll
        for(int half=0; half<2; ++half){
            int f = s*2 + half;
            int row = s*256 + w*32 + half*16 + col;
            const uint_t* src = Mdw + (size_t)row*64 + grp*4;
#pragma unroll
            for(int kt=0;kt<4;++kt)
                wf[f][kt] = *(const v4i*)(src + kt*16);
        }
    }
    // per-lane scale/bias for its own element's 4 gate rows
    float Cs[4], MSs[4];
#pragma unroll
    for(int s=0;s<4;++s){
        int row = s*256 + ge;
        Cs[s]  = ws[WS_CV + row];
        MSs[s] = ws[WS_MS + row];
    }

    // step 0: h0 = 0, x0 = latent -> gh = bhh (exact f32 path, own element)
    const float* gi = ws + WS_GI0 + (size_t)b*768;
    float r0 = sigf(gi[ge]     + bhh[ge]);
    float z0 = sigf(gi[256+ge] + bhh[256+ge]);
    float n0 = tanh_fast(gi[512+ge] + r0*bhh[512+ge]);
    float hp = (1.0f-z0)*n0;

    float* hsp = ws + WS_HSEQ + (size_t)b*256;
    if(grp < 2){
        h8[0][w*32 + (l&31)] = (signed char)__float2int_rn(hp*127.0f);
        hsp[w*32 + (l&31)] = hp;
    }
    asm volatile("s_waitcnt lgkmcnt(0)" ::: "memory");
    __builtin_amdgcn_s_barrier();
    asm volatile("" ::: "memory");

    const v4i vzero = {0,0,0,0};
    int po = 0;
    for(int t=1; t<1028; ++t){
        hsp += 4096;
        v4i af[4];
#pragma unroll
        for(int kt=0;kt<4;++kt)
            af[kt] = *(const v4i*)&h8[po][kt*64 + grp*16];
        v4i acc[8];
#pragma unroll
        for(int f=0;f<8;++f){
            acc[f] = __builtin_amdgcn_mfma_i32_16x16x64_i8(af[0], wf[f][0], vzero, 0,0,0);
#pragma unroll
            for(int kt=1;kt<4;++kt)
                acc[f] = __builtin_amdgcn_mfma_i32_16x16x64_i8(af[kt], wf[f][kt], acc[f], 0,0,0);
        }
        // own element's gates only (static indexing, par-select on values)
        int a_r = par ? acc[1][0] : acc[0][0];
        int a_z = par ? acc[3][0] : acc[2][0];
        int a_n = par ? acc[5][0] : acc[4][0];
        int a_h = par ? acc[7][0] : acc[6][0];
        float yr = MSs[0]*(float)a_r + Cs[0];
        float yz = MSs[1]*(float)a_z + Cs[1];
        float yn = MSs[2]*(float)a_n + Cs[2];
        float yh = MSs[3]*(float)a_h + Cs[3];
        float rr = sigf(yr);
        float zz = sigf(yz);
        float nn = tanh_fast(yn + rr*yh);
        hp = (1.0f-zz)*nn + zz*hp;
        if(grp < 2){
            h8[po^1][w*32 + (l&31)] = (signed char)__float2int_rn(hp*127.0f);
            hsp[w*32 + (l&31)] = hp;
        }
        asm volatile("s_waitcnt lgkmcnt(0)" ::: "memory");
        __builtin_amdgcn_s_barrier();
        asm volatile("" ::: "memory");
        po ^= 1;
    }
}

// ======================= epilogue GEMM =====================================
__global__ __launch_bounds__(256) void k_epi(const float* outW, const float* outb,
                                             const float* ws, float* out){
    __shared__ float ht[16][256];
    int t = blockIdx.x, j = threadIdx.x;
    for(int idx=j; idx<4096; idx+=256)
        ht[idx>>8][idx&255] = ws[WS_HSEQ + (size_t)t*4096 + idx];
    __syncthreads();
    const float* wr = outW + (size_t)j*256;
    float bias = outb[j];
    float acc[16];
#pragma unroll
    for(int bb=0;bb<16;++bb) acc[bb]=bias;
    for(int k=0;k<256;k+=4){
        float4 w4 = *(const float4*)(wr+k);
#pragma unroll
        for(int bb=0;bb<16;++bb)
            acc[bb] += w4.x*ht[bb][k]+w4.y*ht[bb][k+1]+w4.z*ht[bb][k+2]+w4.w*ht[bb][k+3];
    }
#pragma unroll
    for(int bb=0;bb<16;++bb)
        out[(size_t)bb*263168 + (size_t)t*256 + j] = acc[bb];
}

// ======================= launch ============================================

extern "C" void kernel_launch(void* const* d_in, const int* in_sizes, int n_in,
                              void* d_out, int out_size, void* d_ws, size_t ws_size,
                              hipStream_t stream){
    const float* gs   = (const float*)d_in[0];
    const float* eW   = (const float*)d_in[1];
    const float* eb   = (const float*)d_in[2];
    const float* qkvW = (const float*)d_in[3];
    const float* qkvb = (const float*)d_in[4];
    const float* aoW  = (const float*)d_in[5];
    const float* aob  = (const float*)d_in[6];
    const float* g1   = (const float*)d_in[7];
    const float* b1   = (const float*)d_in[8];
    const float* g2   = (const float*)d_in[9];
    const float* b2   = (const float*)d_in[10];
    const float* W1   = (const float*)d_in[11];
    const float* fb1  = (const float*)d_in[12];
    const float* W2   = (const float*)d_in[13];
    const float* fb2  = (const float*)d_in[14];
    const float* Wih  = (const float*)d_in[15];
    const float* Whh  = (const float*)d_in[16];
    const float* bih  = (const float*)d_in[17];
    const float* bhh  = (const float*)d_in[18];
    const float* outW = (const float*)d_in[19];
    const float* outb = (const float*)d_in[20];
    float* ws  = (float*)d_ws;
    float* out = (float*)d_out;

    k_front<<<32,512,0,stream>>>(gs,eW,eb,qkvW,qkvb,aoW,aob,g1,b1,g2,b2,
                                 W1,fb1,W2,fb2,Wih,bih,Whh,bhh,outW,outb,ws);
    k_chain<<<16,512,0,stream>>>(bhh,ws);
    k_epi  <<<1028,256,0,stream>>>(outW,outb,ws,out);
}

// Round 4
// 1096.027 us; speedup vs baseline: 2.1007x; 2.1007x over previous
//
#include <hip/hip_runtime.h>

// ---------------------------------------------------------------------------
// GenomeDecoder: transformer encoder (tiny) -> 1028 sequential GRU steps ->
// output chunks.
// R6: R3-regression revert + width-preserving fusion.  R3 proved collapsing
// to 32 blocks serializes latency chains (k_front 1487us, VALUBusy 1.3%).
// Here: 8 launches, every kernel keeps a wide grid:
//   1. k_emb_prep  (1280 blocks: 256 embed + 1024 one-row prepm, input-only)
//   2. k_qkv_attn  (64 blocks (b,head): own 192 qkv rows, q/k/v in LDS)   x2
//   3. k_ao_ffn    (256 blocks (b,s): ao-matmul+LN1+ffn1+ffn2+LN2, F1 in LDS) x2
//   4. k_lat_gi0   (16 blocks)
//   5. k_chain     (16 blocks, int8 MFMA recurrence, parity-split gates)
//   6. k_epi       (1028 blocks)
// Chain math unchanged: int8 M (per-row scale) x int8 h via
// mfma_i32_16x16x64_i8, h broadcast rows, exact int32 accumulate.
// ---------------------------------------------------------------------------

typedef unsigned int uint_t;
typedef int v4i __attribute__((ext_vector_type(4)));

// ---- workspace layout (4-byte slot indices) ----
static constexpr size_t WS_HB   = 0;        // 16*16*256
static constexpr size_t WS_AO   = 262144;   // 16*16*256
static constexpr size_t WS_GI0  = 593920;   // 16*768
static constexpr size_t WS_CV   = 606208;   // 1024 fused-bias consts
static constexpr size_t WS_MS   = 607232;   // 1024 per-row scales
static constexpr size_t WS_M8   = 608256;   // 1024*64 dwords packed int8 M
static constexpr size_t WS_HSEQ = 673792;   // 1028*16*256 floats

__device__ inline float sigf(float x){
    return __builtin_amdgcn_rcpf(1.0f + __builtin_amdgcn_exp2f(-1.442695041f*x));
}
__device__ inline float tanh_fast(float x){
    return 1.0f - 2.0f*__builtin_amdgcn_rcpf(1.0f + __builtin_amdgcn_exp2f(2.885390082f*x));
}

// ======================= embed + prepm (input-only, wide) ==================
// blocks 0..255: embed row bs = blockIdx.x
// blocks 256..1279: prepm row r = blockIdx.x - 256  (original 1-row form)

__global__ __launch_bounds__(256) void k_emb_prep(
    const float* gs, const float* eW, const float* eb,
    const float* Wih, const float* Whh, const float* bih, const float* bhh,
    const float* outW, const float* outb, float* ws)
{
    __shared__ float wrow[256]; __shared__ float red[256];
    __shared__ signed char q8[256];

    if(blockIdx.x < 256){
        int bs = blockIdx.x;
        int i  = threadIdx.x;
        const float* g = gs + bs*16;
        float acc = eb[i];
#pragma unroll
        for(int d=0; d<16; ++d) acc += g[d]*eW[i*16+d];
        ws[WS_HB + (size_t)bs*256 + i] = acc;
        return;
    }

    int r = blockIdx.x - 256, c = threadIdx.x;
    bool hasA = (r<768);
    wrow[c] = hasA ? Wih[(size_t)r*256+c] : 0.0f;
    __syncthreads();
    float m;
    if(hasA){
        float a=0.f;
        for(int k=0;k<256;++k) a += wrow[k]*outW[(size_t)k*256+c];
        if(r<512) a += Whh[(size_t)r*256+c];
        m=a;
    } else {
        m = Whh[(size_t)(r-256)*256+c];
    }
    // fused bias constant  C = Wih_row . out_b (+ bih/bhh combos)
    red[c] = wrow[c]*outb[c];
    __syncthreads();
    for(int off=128;off>0;off>>=1){ if(c<off) red[c]+=red[c+off]; __syncthreads(); }
    if(c==0){
        float cv;
        if(r<512)       cv = red[0] + bih[r] + bhh[r];
        else if(r<768)  cv = red[0] + bih[r];
        else            cv = bhh[r-256];
        ws[WS_CV + r] = cv;
    }
    __syncthreads();
    // per-row absmax -> int8 quantization
    red[c] = fabsf(m);
    __syncthreads();
    for(int off=128;off>0;off>>=1){ if(c<off) red[c]=fmaxf(red[c],red[c+off]); __syncthreads(); }
    float rowmax = red[0];
    float inv = rowmax>0.f ? 127.0f/rowmax : 0.0f;
    q8[c] = (signed char)__float2int_rn(m*inv);
    if(c==0) ws[WS_MS + r] = rowmax>0.f ? rowmax*(1.0f/(127.0f*127.0f)) : 0.0f;
    __syncthreads();
    if(c<64){
        uint_t u = ((uint_t)(unsigned char)q8[4*c  ])
                 | ((uint_t)(unsigned char)q8[4*c+1] << 8)
                 | ((uint_t)(unsigned char)q8[4*c+2] << 16)
                 | ((uint_t)(unsigned char)q8[4*c+3] << 24);
        ((uint_t*)ws)[WS_M8 + (size_t)r*64 + c] = u;
    }
}

// ======================= qkv + attention, per (b,head) =====================
// 64 blocks: b = blockIdx>>2, head = blockIdx&3.  Each block computes its
// own 192 qkv rows (q/k/v slices of this head) -> LDS only, then attention,
// writes AO.  Zero recompute vs split kernels; kills the WS_QKV round-trip.

__global__ __launch_bounds__(256) void k_qkv_attn(const float* qkvW, const float* qkvb,
                                                  float* ws, int l){
    __shared__ float s_h[16][256];
    __shared__ float s_q[16][64], s_k[16][64], s_v[16][64];
    __shared__ float s_sc[16][16];
    int b = blockIdx.x>>2, hh = blockIdx.x&3;
    int tid = threadIdx.x;

    for(int u=tid; u<4096; u+=256)
        s_h[u>>8][u&255] = ws[WS_HB + (size_t)(b*16+(u>>8))*256 + (u&255)];
    __syncthreads();

    if(tid<192){
        int p = tid>>6, d = tid&63;           // p: 0=q 1=k 2=v
        int row = l*768 + p*256 + hh*64 + d;
        const float* wr = qkvW + (size_t)row*256;
        float bias = qkvb[row];
        float acc[16];
#pragma unroll
        for(int s=0;s<16;++s) acc[s]=bias;
        for(int k=0;k<256;k+=4){
            float4 w4 = *(const float4*)(wr+k);
#pragma unroll
            for(int s=0;s<16;++s){
                float4 h4 = *(const float4*)&s_h[s][k];
                acc[s] += w4.x*h4.x + w4.y*h4.y + w4.z*h4.z + w4.w*h4.w;
            }
        }
        float (*dst)[64] = (p==0) ? s_q : (p==1) ? s_k : s_v;
#pragma unroll
        for(int s=0;s<16;++s) dst[s][d] = acc[s];
    }
    __syncthreads();

    {   // scores
        int s = tid>>4, t = tid&15;
        float a=0.f;
#pragma unroll
        for(int d=0; d<64; ++d) a += s_q[s][d]*s_k[t][d];
        s_sc[s][t] = a*0.125f;
    }
    __syncthreads();
    if(tid<16){
        int r=tid;
        float m=-1e30f;
#pragma unroll
        for(int tt=0;tt<16;++tt) m=fmaxf(m,s_sc[r][tt]);
        float e[16]; float sum=0.f;
#pragma unroll
        for(int tt=0;tt<16;++tt){ e[tt]=__expf(s_sc[r][tt]-m); sum+=e[tt]; }
        float inv=1.0f/sum;
#pragma unroll
        for(int tt=0;tt<16;++tt) s_sc[r][tt]=e[tt]*inv;
    }
    __syncthreads();
    for(int u=tid; u<1024; u+=256){
        int s=u>>6, d=u&63;
        float o=0.f;
#pragma unroll
        for(int t2=0;t2<16;++t2) o += s_sc[s][t2]*s_v[t2][d];
        ws[WS_AO + (size_t)(b*16+s)*256 + hh*64 + d] = o;
    }
}

// ============ attn-out + LN1 + ffn1 + ffn2 + LN2, per (b,s) ================
// 256 blocks: bs = blockIdx.  Fully self-contained token pipeline; F1 row
// stays in LDS (kills WS_F1 round-trip).

__global__ __launch_bounds__(256) void k_ao_ffn(
    const float* aoW, const float* aob, const float* g1, const float* b1,
    const float* W1, const float* fb1, const float* W2, const float* fb2,
    const float* g2, const float* b2v, float* ws, int l)
{
    __shared__ float s_x[256];      // ao row, then h1 row
    __shared__ float s_f1[1024];
    __shared__ float red[256];
    int bs = blockIdx.x, i = threadIdx.x;

    s_x[i] = ws[WS_AO + (size_t)bs*256 + i];
    float hb = ws[WS_HB + (size_t)bs*256 + i];
    __syncthreads();

    // attn-out matvec
    const float* wr = aoW + (size_t)(l*256+i)*256;
    float acc = aob[l*256+i];
    for(int k=0;k<256;k+=4){
        float4 w4 = *(const float4*)(wr+k);
        float4 h4 = *(const float4*)&s_x[k];
        acc += w4.x*h4.x + w4.y*h4.y + w4.z*h4.z + w4.w*h4.w;
    }
    float x = hb + acc;
    // LN1
    red[i]=x; __syncthreads();
    for(int off=128;off>0;off>>=1){ if(i<off) red[i]+=red[i+off]; __syncthreads(); }
    float mn = red[0]*(1.0f/256.0f); __syncthreads();
    float d = x-mn;
    red[i]=d*d; __syncthreads();
    for(int off=128;off>0;off>>=1){ if(i<off) red[i]+=red[i+off]; __syncthreads(); }
    float vv = red[0]*(1.0f/256.0f);
    float h1 = (d / sqrtf(vv+1e-5f))*g1[l*256+i] + b1[l*256+i];
    __syncthreads();                 // matvec reads of s_x all done (LN barriers passed)
    s_x[i] = h1;
    __syncthreads();

    // ffn1: rows i, 256+i, 512+i, 768+i
#pragma unroll
    for(int jj=0;jj<4;++jj){
        int j = jj*256 + i;
        const float* w1r = W1 + (size_t)(l*1024+j)*256;
        float a1 = fb1[l*1024+j];
        for(int k=0;k<256;k+=4){
            float4 w4 = *(const float4*)(w1r+k);
            float4 h4 = *(const float4*)&s_x[k];
            a1 += w4.x*h4.x + w4.y*h4.y + w4.z*h4.z + w4.w*h4.w;
        }
        s_f1[j] = fmaxf(a1, 0.0f);
    }
    __syncthreads();

    // ffn2
    const float* w2r = W2 + (size_t)(l*256+i)*1024;
    float a2 = fb2[l*256+i];
    for(int k=0;k<1024;k+=4){
        float4 w4 = *(const float4*)(w2r+k);
        float4 h4 = *(const float4*)&s_f1[k];
        a2 += w4.x*h4.x + w4.y*h4.y + w4.z*h4.z + w4.w*h4.w;
    }
    float x2 = h1 + a2;
    // LN2
    red[i]=x2; __syncthreads();
    for(int off=128;off>0;off>>=1){ if(i<off) red[i]+=red[i+off]; __syncthreads(); }
    float mn2 = red[0]*(1.0f/256.0f); __syncthreads();
    float d2 = x2-mn2;
    red[i]=d2*d2; __syncthreads();
    for(int off=128;off>0;off>>=1){ if(i<off) red[i]+=red[i+off]; __syncthreads(); }
    float vv2 = red[0]*(1.0f/256.0f);
    float y2 = d2 / sqrtf(vv2+1e-5f);
    ws[WS_HB + (size_t)bs*256 + i] = y2*g2[l*256+i] + b2v[l*256+i];
}

// ======================= latent mean + gi0 =================================

__global__ __launch_bounds__(768) void k_lat_gi0(const float* Wih, const float* bih,
                                                 float* ws){
    __shared__ float lat[256];
    int b=blockIdx.x, j=threadIdx.x;
    if(j<256){
        float a=0.f;
#pragma unroll
        for(int s=0;s<16;++s) a += ws[WS_HB + (size_t)(b*16+s)*256 + j];
        lat[j] = a*(1.0f/16.0f);
    }
    __syncthreads();
    const float* wr = Wih + (size_t)j*256;
    float acc = bih[j];
    for(int k=0;k<256;k+=4){
        float4 w4=*(const float4*)(wr+k);
        float4 l4=*(const float4*)&lat[k];
        acc += w4.x*l4.x + w4.y*l4.y + w4.z*l4.z + w4.w*l4.w;
    }
    ws[WS_GI0 + (size_t)b*768 + j] = acc;
}

// ======================= sequential GRU chain ==============================
// 16 blocks (one per batch), 512 threads = 8 waves.  Wave w owns h slice
// [w*32, w*32+32): 8 B-fragments (4 gate slices x 2 halves) x 4 K-tiles of
// mfma_i32_16x16x64_i8; A = h broadcast to all 16 rows.  Gate parity split:
// lane (col,grp) tracks only element ge = w*32 + (grp&1)*16 + col -> 3
// transcendentals/step.  h double-buffered in LDS; raw s_barrier +
// lgkmcnt-only wait (global h stores never drain vmcnt in-loop).

__global__ __launch_bounds__(512,2) void k_chain(const float* bhh, float* ws){
    __shared__ alignas(16) signed char h8[2][256];
    int tid = threadIdx.x;
    int b   = blockIdx.x;
    int l   = tid & 63;
    int w   = tid >> 6;
    int col = l & 15;
    int grp = l >> 4;
    int par = grp & 1;
    int ge  = w*32 + par*16 + col;    // this lane's h element

    const uint_t* Mdw = (const uint_t*)ws + WS_M8;

    // B fragments (all 8 needed for the MFMAs)
    v4i wf[8][4];
#pragma unroll
    for(int s=0;s<4;++s){
#pragma unroll
        for(int half=0; half<2; ++half){
            int f = s*2 + half;
            int row = s*256 + w*32 + half*16 + col;
            const uint_t* src = Mdw + (size_t)row*64 + grp*4;
#pragma unroll
            for(int kt=0;kt<4;++kt)
                wf[f][kt] = *(const v4i*)(src + kt*16);
        }
    }
    // per-lane scale/bias for its own element's 4 gate rows
    float Cs[4], MSs[4];
#pragma unroll
    for(int s=0;s<4;++s){
        int row = s*256 + ge;
        Cs[s]  = ws[WS_CV + row];
        MSs[s] = ws[WS_MS + row];
    }

    // step 0: h0 = 0, x0 = latent -> gh = bhh (exact f32 path, own element)
    const float* gi = ws + WS_GI0 + (size_t)b*768;
    float r0 = sigf(gi[ge]     + bhh[ge]);
    float z0 = sigf(gi[256+ge] + bhh[256+ge]);
    float n0 = tanh_fast(gi[512+ge] + r0*bhh[512+ge]);
    float hp = (1.0f-z0)*n0;

    float* hsp = ws + WS_HSEQ + (size_t)b*256;
    if(grp < 2){
        h8[0][w*32 + (l&31)] = (signed char)__float2int_rn(hp*127.0f);
        hsp[w*32 + (l&31)] = hp;
    }
    asm volatile("s_waitcnt lgkmcnt(0)" ::: "memory");
    __builtin_amdgcn_s_barrier();
    asm volatile("" ::: "memory");

    const v4i vzero = {0,0,0,0};
    int po = 0;
    for(int t=1; t<1028; ++t){
        hsp += 4096;
        v4i af[4];
#pragma unroll
        for(int kt=0;kt<4;++kt)
            af[kt] = *(const v4i*)&h8[po][kt*64 + grp*16];
        v4i acc[8];
#pragma unroll
        for(int f=0;f<8;++f){
            acc[f] = __builtin_amdgcn_mfma_i32_16x16x64_i8(af[0], wf[f][0], vzero, 0,0,0);
#pragma unroll
            for(int kt=1;kt<4;++kt)
                acc[f] = __builtin_amdgcn_mfma_i32_16x16x64_i8(af[kt], wf[f][kt], acc[f], 0,0,0);
        }
        // own element's gates only (static indexing, par-select on values)
        int a_r = par ? acc[1][0] : acc[0][0];
        int a_z = par ? acc[3][0] : acc[2][0];
        int a_n = par ? acc[5][0] : acc[4][0];
        int a_h = par ? acc[7][0] : acc[6][0];
        float yr = MSs[0]*(float)a_r + Cs[0];
        float yz = MSs[1]*(float)a_z + Cs[1];
        float yn = MSs[2]*(float)a_n + Cs[2];
        float yh = MSs[3]*(float)a_h + Cs[3];
        float rr = sigf(yr);
        float zz = sigf(yz);
        float nn = tanh_fast(yn + rr*yh);
        hp = (1.0f-zz)*nn + zz*hp;
        if(grp < 2){
            h8[po^1][w*32 + (l&31)] = (signed char)__float2int_rn(hp*127.0f);
            hsp[w*32 + (l&31)] = hp;
        }
        asm volatile("s_waitcnt lgkmcnt(0)" ::: "memory");
        __builtin_amdgcn_s_barrier();
        asm volatile("" ::: "memory");
        po ^= 1;
    }
}

// ======================= epilogue GEMM =====================================
__global__ __launch_bounds__(256) void k_epi(const float* outW, const float* outb,
                                             const float* ws, float* out){
    __shared__ float ht[16][256];
    int t = blockIdx.x, j = threadIdx.x;
    for(int idx=j; idx<4096; idx+=256)
        ht[idx>>8][idx&255] = ws[WS_HSEQ + (size_t)t*4096 + idx];
    __syncthreads();
    const float* wr = outW + (size_t)j*256;
    float bias = outb[j];
    float acc[16];
#pragma unroll
    for(int bb=0;bb<16;++bb) acc[bb]=bias;
    for(int k=0;k<256;k+=4){
        float4 w4 = *(const float4*)(wr+k);
#pragma unroll
        for(int bb=0;bb<16;++bb)
            acc[bb] += w4.x*ht[bb][k]+w4.y*ht[bb][k+1]+w4.z*ht[bb][k+2]+w4.w*ht[bb][k+3];
    }
#pragma unroll
    for(int bb=0;bb<16;++bb)
        out[(size_t)bb*263168 + (size_t)t*256 + j] = acc[bb];
}

// ======================= launch ============================================

extern "C" void kernel_launch(void* const* d_in, const int* in_sizes, int n_in,
                              void* d_out, int out_size, void* d_ws, size_t ws_size,
                              hipStream_t stream){
    const float* gs   = (const float*)d_in[0];
    const float* eW   = (const float*)d_in[1];
    const float* eb   = (const float*)d_in[2];
    const float* qkvW = (const float*)d_in[3];
    const float* qkvb = (const float*)d_in[4];
    const float* aoW  = (const float*)d_in[5];
    const float* aob  = (const float*)d_in[6];
    const float* g1   = (const float*)d_in[7];
    const float* b1   = (const float*)d_in[8];
    const float* g2   = (const float*)d_in[9];
    const float* b2   = (const float*)d_in[10];
    const float* W1   = (const float*)d_in[11];
    const float* fb1  = (const float*)d_in[12];
    const float* W2   = (const float*)d_in[13];
    const float* fb2  = (const float*)d_in[14];
    const float* Wih  = (const float*)d_in[15];
    const float* Whh  = (const float*)d_in[16];
    const float* bih  = (const float*)d_in[17];
    const float* bhh  = (const float*)d_in[18];
    const float* outW = (const float*)d_in[19];
    const float* outb = (const float*)d_in[20];
    float* ws  = (float*)d_ws;
    float* out = (float*)d_out;

    k_emb_prep<<<1280,256,0,stream>>>(gs,eW,eb,Wih,Whh,bih,bhh,outW,outb,ws);
    for(int l=0;l<2;++l){
        k_qkv_attn<<<64,256,0,stream>>>(qkvW,qkvb,ws,l);
        k_ao_ffn  <<<256,256,0,stream>>>(aoW,aob,g1,b1,W1,fb1,W2,fb2,g2,b2,ws,l);
    }
    k_lat_gi0<<<16,768,0,stream>>>(Wih,bih,ws);
    k_chain  <<<16,512,0,stream>>>(bhh,ws);
    k_epi    <<<1028,256,0,stream>>>(outW,outb,ws,out);
}